// Round 3
// baseline (265.015 us; speedup 1.0000x reference)
//
#include <hip/hip_runtime.h>
#include <hip/hip_cooperative_groups.h>

namespace cg = cooperative_groups;

// Problem: B=4, H=8, L=128, D=64. All fp32.
// n = b*8+h in [0,32). Single cooperative kernel, 512 blocks x 256 threads,
// two grid.sync()s. LDS 39.4 KB -> 4 blocks/CU; launch_bounds(256,2) -> >=2
// blocks/CU, so 512 blocks are guaranteed co-resident on 256 CUs.

#define EPS 1e-6f
#define BN_EPS 1e-5f

union SMem {
    struct {                       // Phase A
        float sK[128 * 65];        // pK softmax, whole head, padded (+1 -> 2-way alias only)
        float sQ[8 * 64];          // pQ softmax, own 8 rows
        double rs[256], rs2[256];  // J partial reduction
    } a;
    struct {                       // Phase C
        double sd[256], sd2[256];  // h-stats reduction
        float sx[128];             // gate x for the head
        float shbn[128];           // h_bn for own (b,h) rows
        float sjm, sjinv;          // jstats broadcast
    } c;
    struct {                       // Phase D
        double sd[256], sd2[256];  // tstats reduction
    } d;
};

__global__ void __launch_bounds__(256, 2) fused_all(
    const float* __restrict__ Q, const float* __restrict__ K,
    const float* __restrict__ V,
    const float* __restrict__ j_gamma, const float* __restrict__ j_beta,
    const float* __restrict__ h_gamma, const float* __restrict__ h_beta,
    const float* __restrict__ bnH_gamma, const float* __restrict__ bnH_beta,
    float* __restrict__ out,
    float* __restrict__ J, float* __restrict__ hi, float* __restrict__ h_raw,
    double* __restrict__ Jpart, float* __restrict__ t, double* __restrict__ tpart)
{
    cg::grid_group grid = cg::this_grid();
    __shared__ SMem sm;
    const int bid = blockIdx.x;
    const int tid = threadIdx.x;
    const int wave = tid >> 6, lane = tid & 63;

    // ---------------- Phase A: softmaxes (LDS-only), entropy, J + partials ---
    {
        const int n = bid >> 4;            // head (b*8+h)
        const int i0 = (bid & 15) * 8;     // i-tile base
        // softmax(K) for ALL 128 rows of head n (recomputed per tile; cheap)
        for (int rr = 0; rr < 32; ++rr) {
            const int row = wave * 32 + rr;
            float kk = K[(n * 128 + row) * 64 + lane];
            float m = kk;
            for (int off = 32; off > 0; off >>= 1) m = fmaxf(m, __shfl_xor(m, off));
            float e = expf(kk - m);
            float s = e;
            for (int off = 32; off > 0; off >>= 1) s += __shfl_xor(s, off);
            sm.a.sK[row * 65 + lane] = e / s;
        }
        // softmax(Q) + V entropy for own 8 rows (each row exactly once globally)
        for (int rr = 0; rr < 2; ++rr) {
            const int il = wave * 2 + rr;
            const int row = i0 + il;
            const int gbase = (n * 128 + row) * 64 + lane;
            float q = Q[gbase];
            float m = q;
            for (int off = 32; off > 0; off >>= 1) m = fmaxf(m, __shfl_xor(m, off));
            float e = expf(q - m);
            float s = e;
            for (int off = 32; off > 0; off >>= 1) s += __shfl_xor(s, off);
            sm.a.sQ[il * 64 + lane] = e / s;

            float v = V[gbase];
            s = v;
            for (int off = 32; off > 0; off >>= 1) s += __shfl_xor(s, off);
            float vn = fminf(fmaxf(v / (s + EPS), EPS), 1.0f);
            float hv = -vn * log2f(vn);
            hi[gbase] = hv;
            float hs = hv;
            for (int off = 32; off > 0; off >>= 1) hs += __shfl_xor(hs, off);
            if (lane == 0) h_raw[n * 128 + row] = hs;
        }
        __syncthreads();

        double ls = 0.0, ls2 = 0.0;
        for (int s4 = 0; s4 < 4; ++s4) {
            const int p = tid + 256 * s4;
            const int il = p >> 7;
            const int j = p & 127;
            const float* qrow = sm.a.sQ + il * 64;
            const float* krow = sm.a.sK + j * 65;
            float klq = 0.f, klk = 0.f;
            for (int d = 0; d < 64; ++d) {
                const float q = qrow[d];
                const float k = krow[d];
                const float im = 1.0f / (0.5f * (q + k) + EPS);
                klq += q * log2f(q * im + EPS);
                klk += k * log2f(k * im + EPS);
            }
            const float v = 0.5f * klq + 0.5f * klk;
            J[(n * 128 + i0 + il) * 128 + j] = v;
            if (j != i0 + il) { ls += v; ls2 += (double)v * (double)v; }
        }
        sm.a.rs[tid] = ls; sm.a.rs2[tid] = ls2;
        __syncthreads();
        for (int off = 128; off > 0; off >>= 1) {
            if (tid < off) { sm.a.rs[tid] += sm.a.rs[tid + off];
                             sm.a.rs2[tid] += sm.a.rs2[tid + off]; }
            __syncthreads();
        }
        if (tid == 0) { Jpart[2 * bid] = sm.a.rs[0]; Jpart[2 * bid + 1] = sm.a.rs2[0]; }
    }
    grid.sync();

    // ---------------- Phase C: per-head jstats, h-BN, gate, He, t, tpart -----
    if (bid < 32) {
        const int n = bid, hh = n & 7;
        // jstats: combine 64 double partials of head hh (wave 0, shuffles)
        if (wave == 0) {
            const int bI = lane >> 4, it = lane & 15;
            const int pb = (bI * 8 + hh) * 16 + it;
            double s = Jpart[2 * pb], s2 = Jpart[2 * pb + 1];
            for (int off = 32; off > 0; off >>= 1) {
                s += __shfl_xor(s, off);
                s2 += __shfl_xor(s2, off);
            }
            if (lane == 0) {
                const double cnt = 65024.0;   // 4*128*127
                const double mean = s / cnt;
                const double var = s2 / cnt - mean * mean;
                sm.c.sjm = (float)mean;
                sm.c.sjinv = (float)(1.0 / sqrt(var + (double)BN_EPS));
            }
        }
        // h stats over B*L = 512 values of head hh
        {
            double s = 0.0, s2 = 0.0;
            for (int p = tid; p < 512; p += 256) {
                const int b = p >> 7, l = p & 127;
                const float v = h_raw[(b * 8 + hh) * 128 + l];
                s += v; s2 += (double)v * (double)v;
            }
            sm.c.sd[tid] = s; sm.c.sd2[tid] = s2;
        }
        __syncthreads();
        for (int off = 128; off > 0; off >>= 1) {
            if (tid < off) { sm.c.sd[tid] += sm.c.sd[tid + off];
                             sm.c.sd2[tid] += sm.c.sd2[tid + off]; }
            __syncthreads();
        }
        const double hm = sm.c.sd[0] / 512.0;
        const double hvar = sm.c.sd2[0] / 512.0 - hm * hm;
        const float hinv = (float)(1.0 / sqrt(hvar + (double)BN_EPS));
        if (tid < 128) {
            const float v = h_raw[n * 128 + tid];
            sm.c.shbn[tid] = (v - (float)hm) * hinv * h_gamma[hh] + h_beta[hh];
        }
        __syncthreads();
        const float jm = sm.c.sjm, jinv = sm.c.sjinv;
        const float jg = j_gamma[hh], jb = j_beta[hh];
        // gate x[i] from normalized row sums (raw diagonal kept, as reference)
        for (int rr = 0; rr < 32; ++rr) {
            const int i = wave * 32 + rr;
            const int rbase = (n * 128 + i) * 128;
            float v0 = J[rbase + lane], v1 = J[rbase + 64 + lane];
            if (lane != i)      v0 = (v0 - jm) * jinv * jg + jb;
            if (lane + 64 != i) v1 = (v1 - jm) * jinv * jg + jb;
            float s = v0 + v1;
            for (int off = 32; off > 0; off >>= 1) s += __shfl_xor(s, off);
            if (lane == 0)
                sm.c.sx[i] = (s + sm.c.shbn[i] < 0.0f) ? 1.0f : 0.0f;
        }
        __syncthreads();
        // He, t = -(He*hi/h_bn), per-row double partials
        for (int rr = 0; rr < 32; ++rr) {
            const int i = wave * 32 + rr;
            const int r = n * 128 + i;
            const int rbase = r * 128;
            float v0 = J[rbase + lane], v1 = J[rbase + 64 + lane];
            if (lane != i)      v0 = (v0 - jm) * jinv * jg + jb;
            if (lane + 64 != i) v1 = (v1 - jm) * jinv * jg + jb;
            float s = v0 * sm.c.sx[lane] + v1 * sm.c.sx[lane + 64];
            for (int off = 32; off > 0; off >>= 1) s += __shfl_xor(s, off);
            const float hb = sm.c.shbn[i];
            const float He = sm.c.sx[i] * (s + hb);
            const float tv = -(He * hi[r * 64 + lane] / hb);
            t[r * 64 + lane] = tv;
            double ds = tv, ds2 = (double)tv * (double)tv;
            for (int off = 32; off > 0; off >>= 1) {
                ds += __shfl_xor(ds, off);
                ds2 += __shfl_xor(ds2, off);
            }
            if (lane == 0) { tpart[2 * r] = ds; tpart[2 * r + 1] = ds2; }
        }
    }
    grid.sync();

    // ---------------- Phase D: tstats (redundant per block) + final BN write --
    {
        const int g0 = bid * 512;              // 512 outputs per block
        const int hh = (g0 >> 13) & 7;         // uniform: 512 | 8192
        double s = 0.0, s2 = 0.0;
        for (int p = tid; p < 512; p += 256) {
            const int b = p >> 7, i = p & 127;
            const int r = (b * 8 + hh) * 128 + i;
            s += tpart[2 * r]; s2 += tpart[2 * r + 1];
        }
        sm.d.sd[tid] = s; sm.d.sd2[tid] = s2;
        __syncthreads();
        for (int off = 128; off > 0; off >>= 1) {
            if (tid < off) { sm.d.sd[tid] += sm.d.sd[tid + off];
                             sm.d.sd2[tid] += sm.d.sd2[tid + off]; }
            __syncthreads();
        }
        const double mean = sm.d.sd[0] / 32768.0;
        const double var = sm.d.sd2[0] / 32768.0 - mean * mean;
        const float tm = (float)mean;
        const float tinv = (float)(1.0 / sqrt(var + (double)BN_EPS));
        const float g = bnH_gamma[hh], be = bnH_beta[hh];
        out[g0 + tid]       = (t[g0 + tid]       - tm) * tinv * g + be;
        out[g0 + 256 + tid] = (t[g0 + 256 + tid] - tm) * tinv * g + be;
    }
}

// ---------------------------------------------------------------- launch
extern "C" void kernel_launch(void* const* d_in, const int* in_sizes, int n_in,
                              void* d_out, int out_size, void* d_ws, size_t ws_size,
                              hipStream_t stream) {
    const float* Q = (const float*)d_in[0];
    const float* K = (const float*)d_in[1];
    const float* V = (const float*)d_in[2];
    const float* j_gamma = (const float*)d_in[3];
    const float* j_beta  = (const float*)d_in[4];
    const float* h_gamma = (const float*)d_in[5];
    const float* h_beta  = (const float*)d_in[6];
    const float* bnH_gamma = (const float*)d_in[7];
    const float* bnH_beta  = (const float*)d_in[8];
    float* out = (float*)d_out;

    float* w = (float*)d_ws;
    float*  J     = w;                         // 524288 floats (2 MB)
    float*  hi    = w + 524288;                // 262144 floats (1 MB)
    float*  t     = w + 786432;                // 262144 floats (1 MB)
    float*  h_raw = w + 1048576;               // 4096 floats
    double* Jpart = (double*)(w + 1052672);    // 1024 doubles (8B-aligned)
    double* tpart = (double*)(w + 1054720);    // 8192 doubles (8B-aligned)

    void* args[] = { (void*)&Q, (void*)&K, (void*)&V,
                     (void*)&j_gamma, (void*)&j_beta,
                     (void*)&h_gamma, (void*)&h_beta,
                     (void*)&bnH_gamma, (void*)&bnH_beta,
                     (void*)&out, (void*)&J, (void*)&hi, (void*)&h_raw,
                     (void*)&Jpart, (void*)&t, (void*)&tpart };
    hipLaunchCooperativeKernel((void*)fused_all, dim3(512), dim3(256),
                               args, 0, stream);
}

// Round 4
// 155.298 us; speedup vs baseline: 1.7065x; 1.7065x over previous
//
#include <hip/hip_runtime.h>

// Problem: B=4, H=8, L=128, D=64. All fp32.  n = b*8+h in [0,32).
// Three plain kernels (no cooperative launch — grid.sync() cost ~2x the whole
// workload on 8-XCD MI355X; kernel boundaries give cross-XCD visibility free).

#define EPS 1e-6f
#define BN_EPS 1e-5f

// ---------------- KA: 512 blocks x 256 threads -------------------------------
// Per block: softmax(K) for the whole head into LDS (recomputed per tile,
// cheap), softmax(Q)+entropy(V) for own 8 rows, J tile + double partials.
__global__ void __launch_bounds__(256) ka_J(
    const float* __restrict__ Q, const float* __restrict__ K,
    const float* __restrict__ V,
    float* __restrict__ J, float* __restrict__ hi,
    float* __restrict__ h_raw, double* __restrict__ Jpart)
{
    __shared__ float sK[128 * 65];     // +1 pad -> 2-way bank alias only (free)
    __shared__ float sQ[8 * 64];
    __shared__ double rs[256], rs2[256];
    const int bid = blockIdx.x;        // n*16 + it
    const int n = bid >> 4;
    const int i0 = (bid & 15) * 8;
    const int tid = threadIdx.x;
    const int wave = tid >> 6, lane = tid & 63;

    // softmax(K), all 128 rows of head n
    for (int rr = 0; rr < 32; ++rr) {
        const int row = wave * 32 + rr;
        float kk = K[(n * 128 + row) * 64 + lane];
        float m = kk;
        for (int off = 32; off > 0; off >>= 1) m = fmaxf(m, __shfl_xor(m, off));
        float e = expf(kk - m);
        float s = e;
        for (int off = 32; off > 0; off >>= 1) s += __shfl_xor(s, off);
        sK[row * 65 + lane] = e / s;
    }
    // softmax(Q) + entropy(V) for own 8 rows (each row exactly once globally)
    for (int rr = 0; rr < 2; ++rr) {
        const int il = wave * 2 + rr;
        const int row = i0 + il;
        const int gbase = (n * 128 + row) * 64 + lane;
        float q = Q[gbase];
        float m = q;
        for (int off = 32; off > 0; off >>= 1) m = fmaxf(m, __shfl_xor(m, off));
        float e = expf(q - m);
        float s = e;
        for (int off = 32; off > 0; off >>= 1) s += __shfl_xor(s, off);
        sQ[il * 64 + lane] = e / s;

        float v = V[gbase];
        s = v;
        for (int off = 32; off > 0; off >>= 1) s += __shfl_xor(s, off);
        float vn = fminf(fmaxf(v / (s + EPS), EPS), 1.0f);
        float hv = -vn * log2f(vn);
        hi[gbase] = hv;
        float hs = hv;
        for (int off = 32; off > 0; off >>= 1) hs += __shfl_xor(hs, off);
        if (lane == 0) h_raw[n * 128 + row] = hs;
    }
    __syncthreads();

    double ls = 0.0, ls2 = 0.0;
    for (int s4 = 0; s4 < 4; ++s4) {
        const int p = tid + 256 * s4;
        const int il = p >> 7;
        const int j = p & 127;
        const float* qrow = sQ + il * 64;
        const float* krow = sK + j * 65;
        float klq = 0.f, klk = 0.f;
        for (int d = 0; d < 64; ++d) {
            const float q = qrow[d];
            const float k = krow[d];
            const float im = 1.0f / (0.5f * (q + k) + EPS);
            klq += q * log2f(q * im + EPS);
            klk += k * log2f(k * im + EPS);
        }
        const float v = 0.5f * klq + 0.5f * klk;
        J[(n * 128 + i0 + il) * 128 + j] = v;
        if (j != i0 + il) { ls += v; ls2 += (double)v * (double)v; }
    }
    rs[tid] = ls; rs2[tid] = ls2;
    __syncthreads();
    for (int off = 128; off > 0; off >>= 1) {
        if (tid < off) { rs[tid] += rs[tid + off]; rs2[tid] += rs2[tid + off]; }
        __syncthreads();
    }
    if (tid == 0) { Jpart[2 * bid] = rs[0]; Jpart[2 * bid + 1] = rs2[0]; }
}

// ---------------- KB: 32 blocks x 512 threads (one block per head) -----------
// jstats combine, h batch-norm, gate x, He, t, t-partials — all head-local.
__global__ void __launch_bounds__(512) kb_head(
    const float* __restrict__ J, const float* __restrict__ hi,
    const double* __restrict__ Jpart, const float* __restrict__ h_raw,
    const float* __restrict__ j_gamma, const float* __restrict__ j_beta,
    const float* __restrict__ h_gamma, const float* __restrict__ h_beta,
    float* __restrict__ t, double* __restrict__ tpart)
{
    __shared__ double sd[512], sd2[512];
    __shared__ float sx[128], shbn[128];
    __shared__ float sjm, sjinv;
    const int n = blockIdx.x, hh = n & 7;
    const int tid = threadIdx.x;
    const int wave = tid >> 6, lane = tid & 63;

    // jstats: combine 64 double partials of head hh (wave 0, shuffles only)
    if (wave == 0) {
        const int bI = lane >> 4, it = lane & 15;
        const int pb = (bI * 8 + hh) * 16 + it;
        double s = Jpart[2 * pb], s2 = Jpart[2 * pb + 1];
        for (int off = 32; off > 0; off >>= 1) {
            s += __shfl_xor(s, off);
            s2 += __shfl_xor(s2, off);
        }
        if (lane == 0) {
            const double cnt = 65024.0;   // 4*128*127
            const double mean = s / cnt;
            const double var = s2 / cnt - mean * mean;
            sjm = (float)mean;
            sjinv = (float)(1.0 / sqrt(var + (double)BN_EPS));
        }
    }
    // h stats over B*L = 512 values of head hh (one per thread)
    {
        const int b = tid >> 7, l = tid & 127;
        const float v = h_raw[(b * 8 + hh) * 128 + l];
        sd[tid] = v; sd2[tid] = (double)v * (double)v;
    }
    __syncthreads();
    for (int off = 256; off > 0; off >>= 1) {
        if (tid < off) { sd[tid] += sd[tid + off]; sd2[tid] += sd2[tid + off]; }
        __syncthreads();
    }
    const double hm = sd[0] / 512.0;
    const double hvar = sd2[0] / 512.0 - hm * hm;
    const float hinv = (float)(1.0 / sqrt(hvar + (double)BN_EPS));
    if (tid < 128) {
        const float v = h_raw[n * 128 + tid];
        shbn[tid] = (v - (float)hm) * hinv * h_gamma[hh] + h_beta[hh];
    }
    __syncthreads();
    const float jm = sjm, jinv = sjinv;
    const float jg = j_gamma[hh], jb = j_beta[hh];
    // gate x[i] from normalized row sums (raw diagonal kept, as reference)
    for (int rr = 0; rr < 16; ++rr) {
        const int i = wave * 16 + rr;
        const int rbase = (n * 128 + i) * 128;
        float v0 = J[rbase + lane], v1 = J[rbase + 64 + lane];
        if (lane != i)      v0 = (v0 - jm) * jinv * jg + jb;
        if (lane + 64 != i) v1 = (v1 - jm) * jinv * jg + jb;
        float s = v0 + v1;
        for (int off = 32; off > 0; off >>= 1) s += __shfl_xor(s, off);
        if (lane == 0)
            sx[i] = (s + shbn[i] < 0.0f) ? 1.0f : 0.0f;
    }
    __syncthreads();
    // He, t = -(He*hi/h_bn), per-row double partials
    for (int rr = 0; rr < 16; ++rr) {
        const int i = wave * 16 + rr;
        const int r = n * 128 + i;
        const int rbase = r * 128;
        float v0 = J[rbase + lane], v1 = J[rbase + 64 + lane];
        if (lane != i)      v0 = (v0 - jm) * jinv * jg + jb;
        if (lane + 64 != i) v1 = (v1 - jm) * jinv * jg + jb;
        float s = v0 * sx[lane] + v1 * sx[lane + 64];
        for (int off = 32; off > 0; off >>= 1) s += __shfl_xor(s, off);
        const float hb = shbn[i];
        const float He = sx[i] * (s + hb);
        const float tv = -(He * hi[r * 64 + lane] / hb);
        t[r * 64 + lane] = tv;
        double ds = tv, ds2 = (double)tv * (double)tv;
        for (int off = 32; off > 0; off >>= 1) {
            ds += __shfl_xor(ds, off);
            ds2 += __shfl_xor(ds2, off);
        }
        if (lane == 0) { tpart[2 * r] = ds; tpart[2 * r + 1] = ds2; }
    }
}

// ---------------- KC: 512 blocks x 256 threads -------------------------------
// Redundant per-head tstats combine (L2-resident) + final BN write.
__global__ void __launch_bounds__(256) kc_out(
    const double* __restrict__ tpart, const float* __restrict__ t,
    const float* __restrict__ gamma, const float* __restrict__ beta,
    float* __restrict__ out)
{
    __shared__ double sd[256], sd2[256];
    const int bid = blockIdx.x;
    const int tid = threadIdx.x;
    const int g0 = bid * 512;              // 512 outputs per block
    const int hh = (g0 >> 13) & 7;         // uniform within block
    double s = 0.0, s2 = 0.0;
    for (int p = tid; p < 512; p += 256) {
        const int b = p >> 7, i = p & 127;
        const int r = (b * 8 + hh) * 128 + i;
        s += tpart[2 * r]; s2 += tpart[2 * r + 1];
    }
    sd[tid] = s; sd2[tid] = s2;
    __syncthreads();
    for (int off = 128; off > 0; off >>= 1) {
        if (tid < off) { sd[tid] += sd[tid + off]; sd2[tid] += sd2[tid + off]; }
        __syncthreads();
    }
    const double mean = sd[0] / 32768.0;
    const double var = sd2[0] / 32768.0 - mean * mean;
    const float tm = (float)mean;
    const float tinv = (float)(1.0 / sqrt(var + (double)BN_EPS));
    const float g = gamma[hh], be = beta[hh];
    out[g0 + tid]       = (t[g0 + tid]       - tm) * tinv * g + be;
    out[g0 + 256 + tid] = (t[g0 + 256 + tid] - tm) * tinv * g + be;
}

// ---------------------------------------------------------------- launch
extern "C" void kernel_launch(void* const* d_in, const int* in_sizes, int n_in,
                              void* d_out, int out_size, void* d_ws, size_t ws_size,
                              hipStream_t stream) {
    const float* Q = (const float*)d_in[0];
    const float* K = (const float*)d_in[1];
    const float* V = (const float*)d_in[2];
    const float* j_gamma = (const float*)d_in[3];
    const float* j_beta  = (const float*)d_in[4];
    const float* h_gamma = (const float*)d_in[5];
    const float* h_beta  = (const float*)d_in[6];
    const float* bnH_gamma = (const float*)d_in[7];
    const float* bnH_beta  = (const float*)d_in[8];
    float* out = (float*)d_out;

    float* w = (float*)d_ws;
    float*  J     = w;                         // 524288 floats (2 MB)
    float*  hi    = w + 524288;                // 262144 floats (1 MB)
    float*  t     = w + 786432;                // 262144 floats (1 MB)
    float*  h_raw = w + 1048576;               // 4096 floats
    double* Jpart = (double*)(w + 1052672);    // 1024 doubles (8B-aligned)
    double* tpart = (double*)(w + 1054720);    // 8192 doubles (8B-aligned)

    ka_J<<<512, 256, 0, stream>>>(Q, K, V, J, hi, h_raw, Jpart);
    kb_head<<<32, 512, 0, stream>>>(J, hi, Jpart, h_raw,
                                    j_gamma, j_beta, h_gamma, h_beta, t, tpart);
    kc_out<<<512, 256, 0, stream>>>(tpart, t, bnH_gamma, bnH_beta, out);
}

// Round 8
// 124.416 us; speedup vs baseline: 2.1301x; 1.2482x over previous
//
#include <hip/hip_runtime.h>

// Problem: B=4, H=8, L=128, D=64. All fp32.  n = b*8+h in [0,32).
// KA: softmaxes (LDS) + entropies + J via JSD identity (1 log2f per (i,j,d))
//     + raw row sums S, diagonals D, double off-diag partials.
// KC: per-head stats redundantly per block (cheap), gate x via algebra from
//     S/D, T=J·x pass, He, t, t-partials.
// KD: redundant tstats combine + final BN write.
// MATH NAMES: plain exp2f/log2f + __fdividef ONLY. __exp2f/__log2f collide
// with glibc math.h internals (R7 compile failure); __builtin_amdgcn_logf/
// exp2f broke the container in R5/R6. Do not reintroduce them.

#define EPS 1e-6f
#define BN_EPS 1e-5f
#define LOG2E 1.4426950408889634f

__device__ __forceinline__ float frcp(float x) { return __fdividef(1.0f, x); }

// ---------------- KA: 512 blocks x 256 threads -------------------------------
__global__ void __launch_bounds__(256) ka_J(
    const float* __restrict__ Q, const float* __restrict__ K,
    const float* __restrict__ V,
    float* __restrict__ J, float* __restrict__ hi, float* __restrict__ h_raw,
    float* __restrict__ Sg, float* __restrict__ Dg, double* __restrict__ Jpart)
{
    __shared__ float sK[128 * 65];   // +1 pad -> consecutive banks, conflict-free
    __shared__ float sQ[8 * 64];
    __shared__ float sSk[128];       // Sk(j) = sum_d pk*log2(pk)
    __shared__ float sSq[8];
    __shared__ double sred[8];
    const int bid = blockIdx.x;      // n*16 + tile
    const int n = bid >> 4;
    const int i0 = (bid & 15) * 8;
    const int tid = threadIdx.x;
    const int wave = tid >> 6, lane = tid & 63;

    // softmax(K) + Sk for all 128 rows of head n (recomputed per tile; cheap)
    for (int rr = 0; rr < 32; ++rr) {
        const int row = wave * 32 + rr;
        float kk = K[(n * 128 + row) * 64 + lane];
        float m = kk;
        for (int off = 32; off; off >>= 1) m = fmaxf(m, __shfl_xor(m, off));
        float e = exp2f((kk - m) * LOG2E);   // base-2 softmax == base-e softmax
        float s = e;
        for (int off = 32; off; off >>= 1) s += __shfl_xor(s, off);
        const float pk = e * frcp(s);
        sK[row * 65 + lane] = pk;
        float pl = pk * log2f(pk);
        for (int off = 32; off; off >>= 1) pl += __shfl_xor(pl, off);
        if (lane == 0) sSk[row] = pl;
    }
    // softmax(Q) + Sq + entropy(V) for own 8 rows; wave w -> local rows {w, w+4}
    for (int rr = 0; rr < 2; ++rr) {
        const int il = wave + 4 * rr;
        const int row = i0 + il;
        const int gbase = (n * 128 + row) * 64 + lane;
        float q = Q[gbase];
        float m = q;
        for (int off = 32; off; off >>= 1) m = fmaxf(m, __shfl_xor(m, off));
        float e = exp2f((q - m) * LOG2E);
        float s = e;
        for (int off = 32; off; off >>= 1) s += __shfl_xor(s, off);
        const float pq = e * frcp(s);
        sQ[il * 64 + lane] = pq;
        float pl = pq * log2f(pq);
        for (int off = 32; off; off >>= 1) pl += __shfl_xor(pl, off);
        if (lane == 0) sSq[il] = pl;

        float v = V[gbase];
        s = v;
        for (int off = 32; off; off >>= 1) s += __shfl_xor(s, off);
        float vn = v * frcp(s + EPS);
        vn = fminf(fmaxf(vn, EPS), 1.0f);
        const float hv = -vn * log2f(vn);
        hi[gbase] = hv;
        float hs = hv;
        for (int off = 32; off; off >>= 1) hs += __shfl_xor(hs, off);
        if (lane == 0) h_raw[n * 128 + row] = hs;
    }
    __syncthreads();

    // J tile: wave rb -> local rows {rb, rb+4}; lane -> columns {lane, lane+64}.
    // JSD identity: J = 0.5*(Sq(i) + Sk(j) - sum_d s*log2(s/2+EPS)), s=q+k.
    const int rb = wave;
    const int j0 = lane, j1 = lane + 64;
    const float* q0 = sQ + rb * 64;
    const float* q1 = sQ + (rb + 4) * 64;
    const float* k0 = sK + j0 * 65;
    const float* k1 = sK + j1 * 65;
    float a00 = 0.f, a01 = 0.f, a10 = 0.f, a11 = 0.f;
    #pragma unroll 8
    for (int d = 0; d < 64; ++d) {
        const float qa = q0[d], qb = q1[d];
        const float ka = k0[d], kb = k1[d];
        float s;
        s = qa + ka; a00 += s * log2f(0.5f * s + EPS);
        s = qa + kb; a01 += s * log2f(0.5f * s + EPS);
        s = qb + ka; a10 += s * log2f(0.5f * s + EPS);
        s = qb + kb; a11 += s * log2f(0.5f * s + EPS);
    }
    const int gi0 = i0 + rb, gi1 = i0 + rb + 4;     // rows within head [0,128)
    const float J00 = 0.5f * (sSq[rb]     + sSk[j0] - a00);
    const float J01 = 0.5f * (sSq[rb]     + sSk[j1] - a01);
    const float J10 = 0.5f * (sSq[rb + 4] + sSk[j0] - a10);
    const float J11 = 0.5f * (sSq[rb + 4] + sSk[j1] - a11);
    const int rbase0 = (n * 128 + gi0) * 128;
    const int rbase1 = (n * 128 + gi1) * 128;
    J[rbase0 + j0] = J00; J[rbase0 + j1] = J01;
    J[rbase1 + j0] = J10; J[rbase1 + j1] = J11;

    // raw row sums + diagonals (full row lives in this wave)
    float s0 = J00 + J01, s1 = J10 + J11;
    for (int off = 32; off; off >>= 1) {
        s0 += __shfl_xor(s0, off);
        s1 += __shfl_xor(s1, off);
    }
    const float D0 = (gi0 < 64) ? __shfl(J00, gi0) : __shfl(J01, gi0 - 64);
    const float D1 = (gi1 < 64) ? __shfl(J10, gi1) : __shfl(J11, gi1 - 64);
    if (lane == 0) {
        Sg[n * 128 + gi0] = s0; Dg[n * 128 + gi0] = D0;
        Sg[n * 128 + gi1] = s1; Dg[n * 128 + gi1] = D1;
    }

    // off-diagonal double partials (sum, sumsq)
    double ls = 0.0, ls2 = 0.0;
    if (j0 != gi0) { ls += J00; ls2 += (double)J00 * (double)J00; }
    if (j1 != gi0) { ls += J01; ls2 += (double)J01 * (double)J01; }
    if (j0 != gi1) { ls += J10; ls2 += (double)J10 * (double)J10; }
    if (j1 != gi1) { ls += J11; ls2 += (double)J11 * (double)J11; }
    for (int off = 32; off; off >>= 1) {
        ls  += __shfl_xor(ls, off);
        ls2 += __shfl_xor(ls2, off);
    }
    if (lane == 0) { sred[wave] = ls; sred[4 + wave] = ls2; }
    __syncthreads();
    if (tid == 0) {
        Jpart[2 * bid]     = sred[0] + sred[1] + sred[2] + sred[3];
        Jpart[2 * bid + 1] = sred[4] + sred[5] + sred[6] + sred[7];
    }
}

// ---------------- KC: 512 blocks x 256 threads -------------------------------
// Redundant per-head prep (jstats, hstats, gate x via S/D algebra), then
// T = J·x pass for own 8 rows, He, t, t-partials.
__global__ void __launch_bounds__(256) kc_he(
    const float* __restrict__ J, const float* __restrict__ hi,
    const double* __restrict__ Jpart, const float* __restrict__ h_raw,
    const float* __restrict__ Sg, const float* __restrict__ Dg,
    const float* __restrict__ j_gamma, const float* __restrict__ j_beta,
    const float* __restrict__ h_gamma, const float* __restrict__ h_beta,
    float* __restrict__ t, double* __restrict__ tpart)
{
    __shared__ float sx[128], shbn[128];
    __shared__ double sred[8];
    __shared__ float sprm[5];        // jm, jinv, hm, hinv, C
    const int bid = blockIdx.x;
    const int n = bid >> 4;
    const int i0 = (bid & 15) * 8;
    const int hh = n & 7;
    const int tid = threadIdx.x;
    const int wave = tid >> 6, lane = tid & 63;

    // jstats: combine the head's 64 double partials (wave 0)
    if (wave == 0) {
        const int b = lane >> 4, it = lane & 15;
        const int pb = (b * 8 + hh) * 16 + it;
        double s = Jpart[2 * pb], s2 = Jpart[2 * pb + 1];
        for (int off = 32; off; off >>= 1) {
            s += __shfl_xor(s, off); s2 += __shfl_xor(s2, off);
        }
        if (lane == 0) {
            const double cnt = 65024.0;          // 4*128*127
            const double mean = s / cnt;
            const double var = s2 / cnt - mean * mean;
            sprm[0] = (float)mean;
            sprm[1] = (float)(1.0 / sqrt(var + (double)BN_EPS));
        }
    }
    // h stats over 512 values (all waves)
    {
        double s = 0.0, s2 = 0.0;
        for (int p = tid; p < 512; p += 256) {
            const int b = p >> 7, l = p & 127;
            const float v = h_raw[(b * 8 + hh) * 128 + l];
            s += v; s2 += (double)v * (double)v;
        }
        for (int off = 32; off; off >>= 1) {
            s += __shfl_xor(s, off); s2 += __shfl_xor(s2, off);
        }
        if (lane == 0) { sred[wave] = s; sred[4 + wave] = s2; }
    }
    __syncthreads();
    if (tid == 0) {
        const double hs = sred[0] + sred[1] + sred[2] + sred[3];
        const double hs2 = sred[4] + sred[5] + sred[6] + sred[7];
        const double hm = hs / 512.0;
        const double hvar = hs2 / 512.0 - hm * hm;
        sprm[2] = (float)hm;
        sprm[3] = (float)(1.0 / sqrt(hvar + (double)BN_EPS));
    }
    __syncthreads();
    const float jm = sprm[0], jinv = sprm[1];
    const float hm = sprm[2], hinv = sprm[3];
    const float jg = j_gamma[hh], jb = j_beta[hh];
    // gate x + h_bn for all 128 rows of the head (O(1) each via S/D algebra)
    if (tid < 128) {
        const int i = tid;
        const float S = Sg[n * 128 + i], D = Dg[n * 128 + i];
        const float hb = (h_raw[n * 128 + i] - hm) * hinv * h_gamma[hh] + h_beta[hh];
        const float rs = jinv * jg * (S - D - 127.0f * jm) + 127.0f * jb + D;
        sx[i] = (rs + hb < 0.0f) ? 1.0f : 0.0f;
        shbn[i] = hb;
    }
    __syncthreads();
    if (wave == 0) {                 // C = sum of gates
        float c = sx[lane] + sx[lane + 64];
        for (int off = 32; off; off >>= 1) c += __shfl_xor(c, off);
        if (lane == 0) sprm[4] = c;
    }
    __syncthreads();
    const float C = sprm[4];
    // He, t, t-partials for own 8 rows; wave rb -> local rows {rb, rb+4}
    const int rb = wave;
    for (int rr = 0; rr < 2; ++rr) {
        const int i = i0 + rb + 4 * rr;          // row within head
        const int r = n * 128 + i;
        float tr = J[r * 128 + lane] * sx[lane] + J[r * 128 + 64 + lane] * sx[lane + 64];
        for (int off = 32; off; off >>= 1) tr += __shfl_xor(tr, off);
        const float xi = sx[i], Di = Dg[r];
        // sum_j Jnorm_ij*x_j, diagonal raw:
        const float dot = jinv * jg * (tr - xi * Di - jm * (C - xi))
                        + jb * (C - xi) + xi * Di;
        const float He = xi * (dot + shbn[i]);
        const float tv = -(He * hi[r * 64 + lane] * frcp(shbn[i]));
        t[r * 64 + lane] = tv;
        double ds = tv, ds2 = (double)tv * (double)tv;
        for (int off = 32; off; off >>= 1) {
            ds += __shfl_xor(ds, off); ds2 += __shfl_xor(ds2, off);
        }
        if (lane == 0) { tpart[2 * r] = ds; tpart[2 * r + 1] = ds2; }
    }
}

// ---------------- KD: 512 blocks x 256 threads -------------------------------
// Redundant per-head tstats combine (L2-resident) + final BN write.
__global__ void __launch_bounds__(256) kd_out(
    const double* __restrict__ tpart, const float* __restrict__ t,
    const float* __restrict__ gamma, const float* __restrict__ beta,
    float* __restrict__ out)
{
    __shared__ double sd[256], sd2[256];
    const int bid = blockIdx.x;
    const int tid = threadIdx.x;
    const int g0 = bid * 512;              // 512 outputs per block
    const int hh = (g0 >> 13) & 7;         // uniform within block
    double s = 0.0, s2 = 0.0;
    for (int p = tid; p < 512; p += 256) {
        const int b = p >> 7, i = p & 127;
        const int r = (b * 8 + hh) * 128 + i;
        s += tpart[2 * r]; s2 += tpart[2 * r + 1];
    }
    sd[tid] = s; sd2[tid] = s2;
    __syncthreads();
    for (int off = 128; off > 0; off >>= 1) {
        if (tid < off) { sd[tid] += sd[tid + off]; sd2[tid] += sd2[tid + off]; }
        __syncthreads();
    }
    const double mean = sd[0] / 32768.0;
    const double var = sd2[0] / 32768.0 - mean * mean;
    const float tm = (float)mean;
    const float tinv = (float)(1.0 / sqrt(var + (double)BN_EPS));
    const float g = gamma[hh], be = beta[hh];
    out[g0 + tid]       = (t[g0 + tid]       - tm) * tinv * g + be;
    out[g0 + 256 + tid] = (t[g0 + 256 + tid] - tm) * tinv * g + be;
}

// ---------------------------------------------------------------- launch
extern "C" void kernel_launch(void* const* d_in, const int* in_sizes, int n_in,
                              void* d_out, int out_size, void* d_ws, size_t ws_size,
                              hipStream_t stream) {
    (void)in_sizes; (void)n_in; (void)out_size; (void)ws_size;
    const float* Q = (const float*)d_in[0];
    const float* K = (const float*)d_in[1];
    const float* V = (const float*)d_in[2];
    const float* j_gamma = (const float*)d_in[3];
    const float* j_beta  = (const float*)d_in[4];
    const float* h_gamma = (const float*)d_in[5];
    const float* h_beta  = (const float*)d_in[6];
    const float* bnH_gamma = (const float*)d_in[7];
    const float* bnH_beta  = (const float*)d_in[8];
    float* out = (float*)d_out;

    float* w = (float*)d_ws;
    float*  J     = w;                         // 524288 floats (2 MB)
    float*  hi    = w + 524288;                // 262144
    float*  t     = w + 786432;                // 262144
    float*  h_raw = w + 1048576;               // 4096
    float*  Sg    = w + 1052672;               // 4096 raw row sums
    float*  Dg    = w + 1056768;               // 4096 diagonals
    double* Jpart = (double*)(w + 1060864);    // 1024 doubles (8B-aligned)
    double* tpart = (double*)(w + 1062912);    // 8192 doubles (8B-aligned)

    ka_J<<<512, 256, 0, stream>>>(Q, K, V, J, hi, h_raw, Sg, Dg, Jpart);
    kc_he<<<512, 256, 0, stream>>>(J, hi, Jpart, h_raw, Sg, Dg,
                                   j_gamma, j_beta, h_gamma, h_beta, t, tpart);
    kd_out<<<512, 256, 0, stream>>>(tpart, t, bnH_gamma, bnH_beta, out);
}

// Round 10
// 93.128 us; speedup vs baseline: 2.8457x; 1.3360x over previous
//
#include <hip/hip_runtime.h>

// Problem: B=4, H=8, L=128, D=64. All fp32.  n = b*8+h in [0,32).
// K0: per-row softmax(Q), softmax(K), entropies — computed ONCE (4096x64).
// KA: J via JSD identity, 1024 blocks x 4-row tiles, pK staged via float4.
// KC: per-head stats redundantly per block, gate x via S/D algebra, T=J·x,
//     He, t, t-partials.
// KD: redundant tstats combine + final BN write.
// MATH RULES (hard-won):
//   * __log2f/__expf/__fdividef — HIP fast intrinsics -> native v_log/v_exp/
//     v_rcp. These are the ONLY fast transcendental spellings that work here.
//   * plain log2f/exp2f -> OCML precise (~25 VALU) — R8's 51us ka_J.
//   * __exp2f -> glibc collision, compile error (R7).
//   * __builtin_amdgcn_logf / inline-asm v_log_f32 -> container death (R5/R6/R9).

#define EPS 1e-6f
#define BN_EPS 1e-5f

// ---------------- K0: 4096 blocks x 64 threads -------------------------------
// One wave per (b,h,l) row: softmax(Q)->pQ,Sq; softmax(K)->pK,Sk; entropy(V).
__global__ void __launch_bounds__(64) k0_rows(
    const float* __restrict__ Q, const float* __restrict__ K,
    const float* __restrict__ V,
    float* __restrict__ pQ, float* __restrict__ pK,
    float* __restrict__ Sq, float* __restrict__ Sk,
    float* __restrict__ hi, float* __restrict__ h_raw)
{
    const int r = blockIdx.x;          // 0..4095
    const int lane = threadIdx.x;      // 0..63
    const int base = r * 64 + lane;

    // K softmax + Sk
    float kk = K[base];
    float m = kk;
    for (int off = 32; off; off >>= 1) m = fmaxf(m, __shfl_xor(m, off));
    float e = __expf(kk - m);
    float s = e;
    for (int off = 32; off; off >>= 1) s += __shfl_xor(s, off);
    const float pk = e * __fdividef(1.0f, s);
    pK[base] = pk;
    float pl = pk * __log2f(pk);
    for (int off = 32; off; off >>= 1) pl += __shfl_xor(pl, off);
    if (lane == 0) Sk[r] = pl;

    // Q softmax + Sq
    float q = Q[base];
    m = q;
    for (int off = 32; off; off >>= 1) m = fmaxf(m, __shfl_xor(m, off));
    e = __expf(q - m);
    s = e;
    for (int off = 32; off; off >>= 1) s += __shfl_xor(s, off);
    const float pq = e * __fdividef(1.0f, s);
    pQ[base] = pq;
    pl = pq * __log2f(pq);
    for (int off = 32; off; off >>= 1) pl += __shfl_xor(pl, off);
    if (lane == 0) Sq[r] = pl;

    // V entropy
    float v = V[base];
    s = v;
    for (int off = 32; off; off >>= 1) s += __shfl_xor(s, off);
    float vn = v * __fdividef(1.0f, s + EPS);
    vn = fminf(fmaxf(vn, EPS), 1.0f);
    const float hv = -vn * __log2f(vn);
    hi[base] = hv;
    float hs = hv;
    for (int off = 32; off; off >>= 1) hs += __shfl_xor(hs, off);
    if (lane == 0) h_raw[r] = hs;
}

// ---------------- KA: 1024 blocks x 256 threads ------------------------------
// Block = (n, 4-row tile). Stage pK head-slice into LDS (float4, pad 65),
// J via JSD identity: J = 0.5*(Sq(i)+Sk(j) - sum_d s*log2(s/2+EPS)), s=q+k.
// Wave w -> row i0+w; lane -> cols {lane, lane+64}.
__global__ void __launch_bounds__(256) ka_J(
    const float* __restrict__ pQ, const float* __restrict__ pK,
    const float* __restrict__ Sq, const float* __restrict__ Sk,
    float* __restrict__ J, float* __restrict__ Sg, float* __restrict__ Dg,
    double* __restrict__ Jpart)
{
    __shared__ float sK[128 * 65];   // pad 65 -> conflict-free strided reads
    __shared__ float sQ[4 * 64];
    __shared__ float sSk[128];
    __shared__ float sSq[4];
    __shared__ double sred[8];
    const int bid = blockIdx.x;      // n*32 + tile
    const int n = bid >> 5;
    const int i0 = (bid & 31) * 4;
    const int tid = threadIdx.x;
    const int wave = tid >> 6, lane = tid & 63;

    // stage pK slice (128x64 = 2048 float4), pad to 65 floats/row
    const float4* pk4 = (const float4*)(pK + n * 8192);
    #pragma unroll
    for (int v = 0; v < 8; ++v) {
        const int idx = tid + 256 * v;
        const float4 f = pk4[idx];
        float* dst = sK + (idx >> 4) * 65 + (idx & 15) * 4;
        dst[0] = f.x; dst[1] = f.y; dst[2] = f.z; dst[3] = f.w;
    }
    sQ[tid] = pQ[(n * 128 + i0) * 64 + tid];   // 4 rows x 64, contiguous
    if (tid < 128) sSk[tid] = Sk[n * 128 + tid];
    if (tid < 4)   sSq[tid] = Sq[n * 128 + i0 + tid];
    __syncthreads();

    const float* qrow = sQ + wave * 64;
    const float* kp0 = sK + lane * 65;
    const float* kp1 = sK + (lane + 64) * 65;
    float a0 = 0.f, a1 = 0.f;
    #pragma unroll 8
    for (int d = 0; d < 64; ++d) {
        const float qv = qrow[d];
        const float s0v = qv + kp0[d];
        const float s1v = qv + kp1[d];
        a0 += s0v * __log2f(fmaf(0.5f, s0v, EPS));
        a1 += s1v * __log2f(fmaf(0.5f, s1v, EPS));
    }
    const int gi = i0 + wave;                   // row within head
    const float bq = sSq[wave];
    const float J0 = 0.5f * (bq + sSk[lane]      - a0);
    const float J1 = 0.5f * (bq + sSk[lane + 64] - a1);
    const int rbase = (n * 128 + gi) * 128;
    J[rbase + lane] = J0;
    J[rbase + lane + 64] = J1;

    // row sum + diagonal (full row lives in this wave)
    float s0 = J0 + J1;
    for (int off = 32; off; off >>= 1) s0 += __shfl_xor(s0, off);
    const float D = (gi < 64) ? __shfl(J0, gi) : __shfl(J1, gi - 64);
    if (lane == 0) { Sg[n * 128 + gi] = s0; Dg[n * 128 + gi] = D; }

    // off-diagonal double partials
    double ls = 0.0, ls2 = 0.0;
    if (lane != gi)      { ls += J0; ls2 += (double)J0 * (double)J0; }
    if (lane + 64 != gi) { ls += J1; ls2 += (double)J1 * (double)J1; }
    for (int off = 32; off; off >>= 1) {
        ls  += __shfl_xor(ls, off);
        ls2 += __shfl_xor(ls2, off);
    }
    if (lane == 0) { sred[wave] = ls; sred[4 + wave] = ls2; }
    __syncthreads();
    if (tid == 0) {
        Jpart[2 * bid]     = sred[0] + sred[1] + sred[2] + sred[3];
        Jpart[2 * bid + 1] = sred[4] + sred[5] + sred[6] + sred[7];
    }
}

// ---------------- KC: 512 blocks x 256 threads -------------------------------
// Redundant per-head prep (jstats from 128 partials, hstats, gate x via S/D
// algebra), then T = J·x for own 8 rows, He, t, t-partials.
__global__ void __launch_bounds__(256) kc_he(
    const float* __restrict__ J, const float* __restrict__ hi,
    const double* __restrict__ Jpart, const float* __restrict__ h_raw,
    const float* __restrict__ Sg, const float* __restrict__ Dg,
    const float* __restrict__ j_gamma, const float* __restrict__ j_beta,
    const float* __restrict__ h_gamma, const float* __restrict__ h_beta,
    float* __restrict__ t, double* __restrict__ tpart)
{
    __shared__ float sx[128], shbn[128];
    __shared__ double sred[8];
    __shared__ float sprm[5];        // jm, jinv, hm, hinv, C
    const int bid = blockIdx.x;
    const int n = bid >> 4;
    const int i0 = (bid & 15) * 8;
    const int hh = n & 7;
    const int tid = threadIdx.x;
    const int wave = tid >> 6, lane = tid & 63;

    // jstats: combine the head's 128 double partials (wave 0, 2 per lane)
    if (wave == 0) {
        const int p1 = lane, p2 = lane + 64;
        const int pb1 = ((p1 >> 5) * 8 + hh) * 32 + (p1 & 31);
        const int pb2 = ((p2 >> 5) * 8 + hh) * 32 + (p2 & 31);
        double s = Jpart[2 * pb1] + Jpart[2 * pb2];
        double s2 = Jpart[2 * pb1 + 1] + Jpart[2 * pb2 + 1];
        for (int off = 32; off; off >>= 1) {
            s += __shfl_xor(s, off); s2 += __shfl_xor(s2, off);
        }
        if (lane == 0) {
            const double cnt = 65024.0;          // 4*128*127
            const double mean = s / cnt;
            const double var = s2 / cnt - mean * mean;
            sprm[0] = (float)mean;
            sprm[1] = (float)(1.0 / sqrt(var + (double)BN_EPS));
        }
    }
    // h stats over 512 values (all waves)
    {
        double s = 0.0, s2 = 0.0;
        for (int p = tid; p < 512; p += 256) {
            const int b = p >> 7, l = p & 127;
            const float v = h_raw[(b * 8 + hh) * 128 + l];
            s += v; s2 += (double)v * (double)v;
        }
        for (int off = 32; off; off >>= 1) {
            s += __shfl_xor(s, off); s2 += __shfl_xor(s2, off);
        }
        if (lane == 0) { sred[wave] = s; sred[4 + wave] = s2; }
    }
    __syncthreads();
    if (tid == 0) {
        const double hs = sred[0] + sred[1] + sred[2] + sred[3];
        const double hs2 = sred[4] + sred[5] + sred[6] + sred[7];
        const double hm = hs / 512.0;
        const double hvar = hs2 / 512.0 - hm * hm;
        sprm[2] = (float)hm;
        sprm[3] = (float)(1.0 / sqrt(hvar + (double)BN_EPS));
    }
    __syncthreads();
    const float jm = sprm[0], jinv = sprm[1];
    const float hm = sprm[2], hinv = sprm[3];
    const float jg = j_gamma[hh], jb = j_beta[hh];
    // gate x + h_bn for all 128 rows (O(1) each via S/D algebra)
    if (tid < 128) {
        const int i = tid;
        const float S = Sg[n * 128 + i], D = Dg[n * 128 + i];
        const float hb = (h_raw[n * 128 + i] - hm) * hinv * h_gamma[hh] + h_beta[hh];
        const float rs = jinv * jg * (S - D - 127.0f * jm) + 127.0f * jb + D;
        sx[i] = (rs + hb < 0.0f) ? 1.0f : 0.0f;
        shbn[i] = hb;
    }
    __syncthreads();
    if (wave == 0) {                 // C = sum of gates
        float c = sx[lane] + sx[lane + 64];
        for (int off = 32; off; off >>= 1) c += __shfl_xor(c, off);
        if (lane == 0) sprm[4] = c;
    }
    __syncthreads();
    const float C = sprm[4];
    // He, t, t-partials for own 8 rows; wave rb -> local rows {rb, rb+4}
    const int rb = wave;
    for (int rr = 0; rr < 2; ++rr) {
        const int i = i0 + rb + 4 * rr;          // row within head
        const int r = n * 128 + i;
        float tr = J[r * 128 + lane] * sx[lane] + J[r * 128 + 64 + lane] * sx[lane + 64];
        for (int off = 32; off; off >>= 1) tr += __shfl_xor(tr, off);
        const float xi = sx[i], Di = Dg[r];
        const float dot = jinv * jg * (tr - xi * Di - jm * (C - xi))
                        + jb * (C - xi) + xi * Di;
        const float He = xi * (dot + shbn[i]);
        const float tv = -(He * hi[r * 64 + lane] * __fdividef(1.0f, shbn[i]));
        t[r * 64 + lane] = tv;
        double ds = tv, ds2 = (double)tv * (double)tv;
        for (int off = 32; off; off >>= 1) {
            ds += __shfl_xor(ds, off); ds2 += __shfl_xor(ds2, off);
        }
        if (lane == 0) { tpart[2 * r] = ds; tpart[2 * r + 1] = ds2; }
    }
}

// ---------------- KD: 512 blocks x 256 threads -------------------------------
__global__ void __launch_bounds__(256) kd_out(
    const double* __restrict__ tpart, const float* __restrict__ t,
    const float* __restrict__ gamma, const float* __restrict__ beta,
    float* __restrict__ out)
{
    __shared__ double sd[256], sd2[256];
    const int bid = blockIdx.x;
    const int tid = threadIdx.x;
    const int g0 = bid * 512;              // 512 outputs per block
    const int hh = (g0 >> 13) & 7;         // uniform within block
    double s = 0.0, s2 = 0.0;
    for (int p = tid; p < 512; p += 256) {
        const int b = p >> 7, i = p & 127;
        const int r = (b * 8 + hh) * 128 + i;
        s += tpart[2 * r]; s2 += tpart[2 * r + 1];
    }
    sd[tid] = s; sd2[tid] = s2;
    __syncthreads();
    for (int off = 128; off > 0; off >>= 1) {
        if (tid < off) { sd[tid] += sd[tid + off]; sd2[tid] += sd2[tid + off]; }
        __syncthreads();
    }
    const double mean = sd[0] / 32768.0;
    const double var = sd2[0] / 32768.0 - mean * mean;
    const float tm = (float)mean;
    const float tinv = (float)(1.0 / sqrt(var + (double)BN_EPS));
    const float g = gamma[hh], be = beta[hh];
    out[g0 + tid]       = (t[g0 + tid]       - tm) * tinv * g + be;
    out[g0 + 256 + tid] = (t[g0 + 256 + tid] - tm) * tinv * g + be;
}

// ---------------------------------------------------------------- launch
extern "C" void kernel_launch(void* const* d_in, const int* in_sizes, int n_in,
                              void* d_out, int out_size, void* d_ws, size_t ws_size,
                              hipStream_t stream) {
    (void)in_sizes; (void)n_in; (void)out_size; (void)ws_size;
    const float* Q = (const float*)d_in[0];
    const float* K = (const float*)d_in[1];
    const float* V = (const float*)d_in[2];
    const float* j_gamma = (const float*)d_in[3];
    const float* j_beta  = (const float*)d_in[4];
    const float* h_gamma = (const float*)d_in[5];
    const float* h_beta  = (const float*)d_in[6];
    const float* bnH_gamma = (const float*)d_in[7];
    const float* bnH_beta  = (const float*)d_in[8];
    float* out = (float*)d_out;

    float* w = (float*)d_ws;
    float*  J     = w;                         // 524288
    float*  hi    = w + 524288;                // 262144
    float*  t     = w + 786432;                // 262144
    float*  pQ    = w + 1048576;               // 262144
    float*  pK    = w + 1310720;               // 262144 (16B-aligned for float4)
    float*  h_raw = w + 1572864;               // 4096
    float*  Sq    = w + 1576960;               // 4096
    float*  Sk    = w + 1581056;               // 4096
    float*  Sg    = w + 1585152;               // 4096
    float*  Dg    = w + 1589248;               // 4096
    double* Jpart = (double*)(w + 1593344);    // 2048 doubles (8B-aligned)
    double* tpart = (double*)(w + 1597440);    // 8192 doubles (8B-aligned)

    k0_rows<<<4096, 64, 0, stream>>>(Q, K, V, pQ, pK, Sq, Sk, hi, h_raw);
    ka_J<<<1024, 256, 0, stream>>>(pQ, pK, Sq, Sk, J, Sg, Dg, Jpart);
    kc_he<<<512, 256, 0, stream>>>(J, hi, Jpart, h_raw, Sg, Dg,
                                   j_gamma, j_beta, h_gamma, h_beta, t, tpart);
    kd_out<<<512, 256, 0, stream>>>(tpart, t, bnH_gamma, bnH_beta, out);
}